// Round 4
// baseline (388.913 us; speedup 1.0000x reference)
//
#include <hip/hip_runtime.h>

// ---------------------------------------------------------------------------
// TorsoGCNv1: 3x GCNConv(+ReLU) -> global mean pool -> Linear head
// Round 4: GEMM with K-staged LDS (20KB) + bank-swizzled W layout (chunk
// stride 10 floats -> conflict-free reads). Rest unchanged from round 3.
// ---------------------------------------------------------------------------

// ---- CSR build -------------------------------------------------------------

__global__ void deg_count_kernel(const int* __restrict__ dst, int* __restrict__ deg, int E) {
    int e = blockIdx.x * blockDim.x + threadIdx.x;
    if (e < E) atomicAdd(&deg[dst[e]], 1);
}

__global__ void scan1_kernel(const int* __restrict__ deg, int* __restrict__ off,
                             int* __restrict__ bsums, int N) {
    __shared__ int s[256];
    const int tid = threadIdx.x;
    const int i = blockIdx.x * 256 + tid;
    const int v = (i < N) ? deg[i] : 0;
    s[tid] = v;
    __syncthreads();
    for (int o = 1; o < 256; o <<= 1) {
        int t = (tid >= o) ? s[tid - o] : 0;
        __syncthreads();
        s[tid] += t;
        __syncthreads();
    }
    if (i < N) off[i] = s[tid] - v;            // exclusive within block
    if (tid == 255) bsums[blockIdx.x] = s[255];
}

__global__ void scan2_kernel(int* __restrict__ bsums, int NB) {
    __shared__ int s[256];
    const int tid = threadIdx.x;
    const int v = (tid < NB) ? bsums[tid] : 0;
    s[tid] = v;
    __syncthreads();
    for (int o = 1; o < 256; o <<= 1) {
        int t = (tid >= o) ? s[tid - o] : 0;
        __syncthreads();
        s[tid] += t;
        __syncthreads();
    }
    if (tid < NB) bsums[tid] = s[tid] - v;
}

__global__ void scan3_kernel(int* __restrict__ off, const int* __restrict__ bsums,
                             int* __restrict__ cursor, const int* __restrict__ deg,
                             float* __restrict__ dis, int N, int E) {
    const int i = blockIdx.x * 256 + threadIdx.x;
    if (i < N) {
        const int o = off[i] + bsums[blockIdx.x];
        off[i] = o;
        cursor[i] = o;
        dis[i] = rsqrtf((float)deg[i] + 1.0f);
    }
    if (i == 0) off[N] = E;
}

__global__ void fill_csr_kernel(const int* __restrict__ src, const int* __restrict__ dst,
                                int* __restrict__ cursor, int* __restrict__ csr_src, int E) {
    int e = blockIdx.x * blockDim.x + threadIdx.x;
    if (e < E) {
        const int pos = atomicAdd(&cursor[dst[e]], 1);
        csr_src[pos] = src[e];
    }
}

// ---- dense: h[n][c] = dis[n] * sum_k x[n][k] * W[k][c] ---------------------
// W staged in LDS KSTAGE rows at a time; 8-float c-chunk t stored at float
// offset t*10 (pad 2) so chunk start banks 10t mod 32 are all distinct ->
// conflict-free reads. Accumulators persist across K stages.
template <int K, int C, int NR>
__global__ __launch_bounds__(256) void gemm_scale_kernel(
        const float* __restrict__ x, const float* __restrict__ W,
        const float* __restrict__ dis, float* __restrict__ h, int N) {
    constexpr int TC     = C / 8;        // c-chunks (threads along c)
    constexpr int TN     = 256 / TC;     // threads along n
    constexpr int NPB    = NR * TN;      // nodes per block
    constexpr int KSTAGE = 32;           // K rows staged per LDS fill
    constexpr int RS     = TC * 10;      // swizzled row stride (floats)
    __shared__ float Ws[KSTAGE * RS];

    const int tc = threadIdx.x % TC;
    const int tn = threadIdx.x / TC;
    const int c0 = tc * 8;
    const int n0 = blockIdx.x * NPB + tn * NR;

    float acc[NR][8] = {};

    for (int ks = 0; ks < K; ks += KSTAGE) {
        // stage KSTAGE x C weights, swizzled
        for (int idx = threadIdx.x; idx < KSTAGE * (C / 4); idx += 256) {
            const int k  = idx / (C / 4);
            const int f4 = idx % (C / 4);
            const int t  = f4 >> 1;
            const int hh = f4 & 1;
            const float4 v = *reinterpret_cast<const float4*>(&W[(size_t)(ks + k) * C + t * 8 + hh * 4]);
            *reinterpret_cast<float4*>(&Ws[k * RS + t * 10 + hh * 4]) = v;
        }
        __syncthreads();

        for (int k = 0; k < KSTAGE; k += 4) {
            float4 xv[NR];
#pragma unroll
            for (int i = 0; i < NR; ++i) {
                const int nn = n0 + i;
                xv[i] = (nn < N) ? *reinterpret_cast<const float4*>(&x[(size_t)nn * K + ks + k])
                                 : float4{0.f, 0.f, 0.f, 0.f};
            }
#pragma unroll
            for (int kk = 0; kk < 4; ++kk) {
                float wv[8];
#pragma unroll
                for (int j = 0; j < 8; ++j) wv[j] = Ws[(k + kk) * RS + tc * 10 + j];
#pragma unroll
                for (int i = 0; i < NR; ++i) {
                    const float xs = (&xv[i].x)[kk];
#pragma unroll
                    for (int j = 0; j < 8; ++j) acc[i][j] = fmaf(xs, wv[j], acc[i][j]);
                }
            }
        }
        __syncthreads();
    }

#pragma unroll
    for (int i = 0; i < NR; ++i) {
        const int nn = n0 + i;
        if (nn < N) {
            const float d = dis[nn];
#pragma unroll
            for (int j = 0; j < 8; j += 4) {
                float4 r = { acc[i][j] * d, acc[i][j + 1] * d, acc[i][j + 2] * d, acc[i][j + 3] * d };
                *reinterpret_cast<float4*>(&h[(size_t)nn * C + c0 + j]) = r;
            }
        }
    }
}

// ---- aggregate (gather) + self-loop + scale + bias + ReLU, fused ----------
template <int C>
__global__ void gather_kernel(const float* __restrict__ h, const int* __restrict__ off,
                              const int* __restrict__ csr_src, const float* __restrict__ dis,
                              const float* __restrict__ b, float* __restrict__ out, int N) {
    constexpr int CQ = C / 4;
    const long long tid = (long long)blockIdx.x * blockDim.x + threadIdx.x;
    const int node = (int)(tid / CQ);
    const int q    = (int)(tid % CQ);
    if (node >= N) return;

    const int beg = off[node];
    const int end = off[node + 1];

    float4 acc = *reinterpret_cast<const float4*>(&h[(size_t)node * C + q * 4]);  // self loop
    int i = beg;
    for (; i + 2 <= end; i += 2) {
        const int s0 = csr_src[i];
        const int s1 = csr_src[i + 1];
        const float4 v0 = *reinterpret_cast<const float4*>(&h[(size_t)s0 * C + q * 4]);
        const float4 v1 = *reinterpret_cast<const float4*>(&h[(size_t)s1 * C + q * 4]);
        acc.x += v0.x + v1.x; acc.y += v0.y + v1.y;
        acc.z += v0.z + v1.z; acc.w += v0.w + v1.w;
    }
    if (i < end) {
        const int s = csr_src[i];
        const float4 v = *reinterpret_cast<const float4*>(&h[(size_t)s * C + q * 4]);
        acc.x += v.x; acc.y += v.y; acc.z += v.z; acc.w += v.w;
    }
    const float d = dis[node];
    float4 r;
    r.x = fmaf(acc.x, d, b[q * 4 + 0]);
    r.y = fmaf(acc.y, d, b[q * 4 + 1]);
    r.z = fmaf(acc.z, d, b[q * 4 + 2]);
    r.w = fmaf(acc.w, d, b[q * 4 + 3]);
    r.x = r.x > 0.0f ? r.x : 0.0f;
    r.y = r.y > 0.0f ? r.y : 0.0f;
    r.z = r.z > 0.0f ? r.z : 0.0f;
    r.w = r.w > 0.0f ? r.w : 0.0f;
    *reinterpret_cast<float4*>(&out[(size_t)node * C + q * 4]) = r;
}

// ---- pooling (run-length, batch sorted) + head -----------------------------
__global__ void pool_kernel(const float* __restrict__ x3, const int* __restrict__ batch,
                            float* __restrict__ pooled, float* __restrict__ counts, int N) {
    const long long tid = (long long)blockIdx.x * blockDim.x + threadIdx.x;
    const int ch = (int)(tid % 32);
    int n = (int)(tid / 32) * 8;
    if (n >= N) return;
    const int nEnd = (n + 8 < N) ? n + 8 : N;
    int g = batch[n];
    float acc = 0.0f, cnt = 0.0f;
    for (; n < nEnd; ++n) {
        const int gn = batch[n];
        if (gn != g) {
            atomicAdd(&pooled[g * 32 + ch], acc);
            if (ch == 0) atomicAdd(&counts[g], cnt);
            acc = 0.0f; cnt = 0.0f; g = gn;
        }
        acc += x3[(size_t)n * 32 + ch];
        cnt += 1.0f;
    }
    atomicAdd(&pooled[g * 32 + ch], acc);
    if (ch == 0) atomicAdd(&counts[g], cnt);
}

__global__ void head_kernel(const float* __restrict__ pooled, const float* __restrict__ counts,
                            const float* __restrict__ Wl, const float* __restrict__ bl,
                            float* __restrict__ out) {
    __shared__ float p[32];
    const int g = blockIdx.x;
    if (threadIdx.x < 32) {
        float cnt = counts[g];
        cnt = cnt < 1.0f ? 1.0f : cnt;
        p[threadIdx.x] = pooled[g * 32 + threadIdx.x] / cnt;
    }
    __syncthreads();
    const int j = threadIdx.x;  // blockDim.x == 768
    float acc = bl[j];
#pragma unroll
    for (int k = 0; k < 32; ++k) acc = fmaf(p[k], Wl[k * 768 + j], acc);
    out[g * 768 + j] = acc;
}

// ---------------------------------------------------------------------------

extern "C" void kernel_launch(void* const* d_in, const int* in_sizes, int n_in,
                              void* d_out, int out_size, void* d_ws, size_t ws_size,
                              hipStream_t stream) {
    const float* x   = (const float*)d_in[0];
    const float* W1  = (const float*)d_in[1];
    const float* b1  = (const float*)d_in[2];
    const float* W2  = (const float*)d_in[3];
    const float* b2  = (const float*)d_in[4];
    const float* W3  = (const float*)d_in[5];
    const float* b3  = (const float*)d_in[6];
    const float* Wl  = (const float*)d_in[7];
    const float* bl  = (const float*)d_in[8];
    const int* ei    = (const int*)d_in[9];
    const int* batch = (const int*)d_in[10];

    const int N = in_sizes[0] / 128;    // 40000
    const int E = in_sizes[9] / 2;      // 640000
    const int G = out_size / 768;       // 256
    const int NB = (N + 255) / 256;     // scan blocks (<= 256 required)

    const int* src = ei;
    const int* dst = ei + E;
    float* out = (float*)d_out;

    // Workspace:
    //  floats: H[N*128] | A[N*128] | B[N*64] | dis[N] | pooled[G*32] | counts[G]
    //  ints:   deg[N] | off[N+1] | cursor[N] | bsums[256] | csr_src[E]
    float* H      = (float*)d_ws;
    float* A      = H + (size_t)N * 128;
    float* Bb     = A + (size_t)N * 128;
    float* dis    = Bb + (size_t)N * 64;
    float* pooled = dis + N;
    float* counts = pooled + (size_t)G * 32;
    int* deg      = (int*)(counts + G);
    int* off      = deg + N;
    int* cursor   = off + (N + 1);
    int* bsums    = cursor + N;
    int* csr_src  = bsums + 256;

    // ---- CSR build (every launch; ws is re-poisoned) ----
    hipMemsetAsync(deg, 0, (size_t)N * sizeof(int), stream);
    hipMemsetAsync(pooled, 0, ((size_t)G * 32 + G) * sizeof(float), stream);
    deg_count_kernel<<<(E + 255) / 256, 256, 0, stream>>>(dst, deg, E);
    scan1_kernel<<<NB, 256, 0, stream>>>(deg, off, bsums, N);
    scan2_kernel<<<1, 256, 0, stream>>>(bsums, NB);
    scan3_kernel<<<NB, 256, 0, stream>>>(off, bsums, cursor, deg, dis, N, E);
    fill_csr_kernel<<<(E + 255) / 256, 256, 0, stream>>>(src, dst, cursor, csr_src, E);

    // ---- Layer 1: 128 -> 128 : x -> A   (NPB = 4*16 = 64 nodes/block)
    gemm_scale_kernel<128, 128, 4><<<(N + 63) / 64, 256, 0, stream>>>(x, W1, dis, H, N);
    gather_kernel<128><<<(int)(((long long)N * 32 + 255) / 256), 256, 0, stream>>>(
        H, off, csr_src, dis, b1, A, N);

    // ---- Layer 2: 128 -> 64 : A -> B    (NPB = 2*32 = 64 nodes/block)
    gemm_scale_kernel<128, 64, 2><<<(N + 63) / 64, 256, 0, stream>>>(A, W2, dis, H, N);
    gather_kernel<64><<<(int)(((long long)N * 16 + 255) / 256), 256, 0, stream>>>(
        H, off, csr_src, dis, b2, Bb, N);

    // ---- Layer 3: 64 -> 32 : B -> A     (NPB = 2*64 = 128 nodes/block)
    gemm_scale_kernel<64, 32, 2><<<(N + 127) / 128, 256, 0, stream>>>(Bb, W3, dis, H, N);
    gather_kernel<32><<<(int)(((long long)N * 8 + 255) / 256), 256, 0, stream>>>(
        H, off, csr_src, dis, b3, A, N);

    // ---- Global mean pool + head
    pool_kernel<<<(int)(((long long)((N + 7) / 8) * 32 + 255) / 256), 256, 0, stream>>>(
        A, batch, pooled, counts, N);
    head_kernel<<<G, 768, 0, stream>>>(pooled, counts, Wl, bl, out);
}

// Round 5
// 299.521 us; speedup vs baseline: 1.2984x; 1.2984x over previous
//
#include <hip/hip_runtime.h>

// ---------------------------------------------------------------------------
// TorsoGCNv1: 3x GCNConv(+ReLU) -> global mean pool -> Linear head
// Round 5: GEMM v3 — x AND W staged in LDS (aligned, conflict-free layouts),
// register use capped (__launch_bounds__(256,4), controlled unrolling).
// Gather: 4-deep unroll for MLP.
// ---------------------------------------------------------------------------

// ---- CSR build -------------------------------------------------------------

__global__ void deg_count_kernel(const int* __restrict__ dst, int* __restrict__ deg, int E) {
    int e = blockIdx.x * blockDim.x + threadIdx.x;
    if (e < E) atomicAdd(&deg[dst[e]], 1);
}

__global__ void scan1_kernel(const int* __restrict__ deg, int* __restrict__ off,
                             int* __restrict__ bsums, int N) {
    __shared__ int s[256];
    const int tid = threadIdx.x;
    const int i = blockIdx.x * 256 + tid;
    const int v = (i < N) ? deg[i] : 0;
    s[tid] = v;
    __syncthreads();
    for (int o = 1; o < 256; o <<= 1) {
        int t = (tid >= o) ? s[tid - o] : 0;
        __syncthreads();
        s[tid] += t;
        __syncthreads();
    }
    if (i < N) off[i] = s[tid] - v;            // exclusive within block
    if (tid == 255) bsums[blockIdx.x] = s[255];
}

__global__ void scan2_kernel(int* __restrict__ bsums, int NB) {
    __shared__ int s[256];
    const int tid = threadIdx.x;
    const int v = (tid < NB) ? bsums[tid] : 0;
    s[tid] = v;
    __syncthreads();
    for (int o = 1; o < 256; o <<= 1) {
        int t = (tid >= o) ? s[tid - o] : 0;
        __syncthreads();
        s[tid] += t;
        __syncthreads();
    }
    if (tid < NB) bsums[tid] = s[tid] - v;
}

__global__ void scan3_kernel(int* __restrict__ off, const int* __restrict__ bsums,
                             int* __restrict__ cursor, const int* __restrict__ deg,
                             float* __restrict__ dis, int N, int E) {
    const int i = blockIdx.x * 256 + threadIdx.x;
    if (i < N) {
        const int o = off[i] + bsums[blockIdx.x];
        off[i] = o;
        cursor[i] = o;
        dis[i] = rsqrtf((float)deg[i] + 1.0f);
    }
    if (i == 0) off[N] = E;
}

__global__ void fill_csr_kernel(const int* __restrict__ src, const int* __restrict__ dst,
                                int* __restrict__ cursor, int* __restrict__ csr_src, int E) {
    int e = blockIdx.x * blockDim.x + threadIdx.x;
    if (e < E) {
        const int pos = atomicAdd(&cursor[dst[e]], 1);
        csr_src[pos] = src[e];
    }
}

// ---- dense: h[n][c] = dis[n] * sum_k x[n][k] * W[k][c] ---------------------
// Both operands staged in LDS per K-stage of 32:
//   Xs: [NPB][36]  (row stride 36 floats = 144B, 16B aligned; 2-way banks)
//   Ws: [32][TC*12] (8-float chunk t at offset t*12 = 48B aligned; <=2-way)
// Thread (tn,tc) computes NR nodes x 8 channels. Unrolling explicitly limited
// and VGPR capped to keep 4 waves/SIMD (round-4 lesson: 256 VGPRs -> 9% occ).
template <int K, int C, int NR>
__global__ __launch_bounds__(256, 4) void gemm_scale_kernel(
        const float* __restrict__ x, const float* __restrict__ W,
        const float* __restrict__ dis, float* __restrict__ h, int N) {
    constexpr int TC     = C / 8;         // c-chunks
    constexpr int TN     = 256 / TC;      // threads along n
    constexpr int NPB    = NR * TN;       // nodes per block
    constexpr int KSTAGE = 32;
    constexpr int XROW   = KSTAGE + 4;    // 36 floats
    constexpr int WROW   = TC * 12;
    __shared__ float Xs[NPB * XROW];
    __shared__ float Ws[KSTAGE * WROW];

    const int tc = threadIdx.x % TC;
    const int tn = threadIdx.x / TC;
    const int c0 = tc * 8;
    const int nBase = blockIdx.x * NPB;
    const int n0 = nBase + tn * NR;

    float acc[NR][8] = {};

#pragma unroll 1
    for (int ks = 0; ks < K; ks += KSTAGE) {
        // stage W (swizzled chunks)
        for (int idx = threadIdx.x; idx < KSTAGE * (C / 4); idx += 256) {
            const int k  = idx / (C / 4);
            const int f4 = idx % (C / 4);
            const int t  = f4 >> 1;
            const int hh = f4 & 1;
            *reinterpret_cast<float4*>(&Ws[k * WROW + t * 12 + hh * 4]) =
                *reinterpret_cast<const float4*>(&W[(size_t)(ks + k) * C + t * 8 + hh * 4]);
        }
        // stage x tile (coalesced)
        for (int idx = threadIdx.x; idx < NPB * (KSTAGE / 4); idx += 256) {
            const int row = idx / (KSTAGE / 4);
            const int c4  = (idx % (KSTAGE / 4)) * 4;
            const int nn  = nBase + row;
            const float4 v = (nn < N)
                ? *reinterpret_cast<const float4*>(&x[(size_t)nn * K + ks + c4])
                : float4{0.f, 0.f, 0.f, 0.f};
            *reinterpret_cast<float4*>(&Xs[row * XROW + c4]) = v;
        }
        __syncthreads();

#pragma unroll 2
        for (int k = 0; k < KSTAGE; k += 4) {
            float4 xv[NR];
#pragma unroll
            for (int i = 0; i < NR; ++i)
                xv[i] = *reinterpret_cast<const float4*>(&Xs[(tn * NR + i) * XROW + k]);
#pragma unroll
            for (int kk = 0; kk < 4; ++kk) {
                float wv[8];
                *reinterpret_cast<float4*>(&wv[0]) =
                    *reinterpret_cast<const float4*>(&Ws[(k + kk) * WROW + tc * 12]);
                *reinterpret_cast<float4*>(&wv[4]) =
                    *reinterpret_cast<const float4*>(&Ws[(k + kk) * WROW + tc * 12 + 4]);
#pragma unroll
                for (int i = 0; i < NR; ++i) {
                    const float xs = (&xv[i].x)[kk];
#pragma unroll
                    for (int j = 0; j < 8; ++j) acc[i][j] = fmaf(xs, wv[j], acc[i][j]);
                }
            }
        }
        __syncthreads();
    }

#pragma unroll
    for (int i = 0; i < NR; ++i) {
        const int nn = n0 + i;
        if (nn < N) {
            const float d = dis[nn];
#pragma unroll
            for (int j = 0; j < 8; j += 4) {
                float4 r = { acc[i][j] * d, acc[i][j + 1] * d, acc[i][j + 2] * d, acc[i][j + 3] * d };
                *reinterpret_cast<float4*>(&h[(size_t)nn * C + c0 + j]) = r;
            }
        }
    }
}

// ---- aggregate (gather) + self-loop + scale + bias + ReLU, fused ----------
template <int C>
__global__ void gather_kernel(const float* __restrict__ h, const int* __restrict__ off,
                              const int* __restrict__ csr_src, const float* __restrict__ dis,
                              const float* __restrict__ b, float* __restrict__ out, int N) {
    constexpr int CQ = C / 4;
    const long long tid = (long long)blockIdx.x * blockDim.x + threadIdx.x;
    const int node = (int)(tid / CQ);
    const int q    = (int)(tid % CQ);
    if (node >= N) return;

    const int beg = off[node];
    const int end = off[node + 1];

    float4 acc = *reinterpret_cast<const float4*>(&h[(size_t)node * C + q * 4]);  // self loop
    int i = beg;
    for (; i + 4 <= end; i += 4) {
        const int s0 = csr_src[i];
        const int s1 = csr_src[i + 1];
        const int s2 = csr_src[i + 2];
        const int s3 = csr_src[i + 3];
        const float4 v0 = *reinterpret_cast<const float4*>(&h[(size_t)s0 * C + q * 4]);
        const float4 v1 = *reinterpret_cast<const float4*>(&h[(size_t)s1 * C + q * 4]);
        const float4 v2 = *reinterpret_cast<const float4*>(&h[(size_t)s2 * C + q * 4]);
        const float4 v3 = *reinterpret_cast<const float4*>(&h[(size_t)s3 * C + q * 4]);
        acc.x += (v0.x + v1.x) + (v2.x + v3.x);
        acc.y += (v0.y + v1.y) + (v2.y + v3.y);
        acc.z += (v0.z + v1.z) + (v2.z + v3.z);
        acc.w += (v0.w + v1.w) + (v2.w + v3.w);
    }
    for (; i < end; ++i) {
        const int s = csr_src[i];
        const float4 v = *reinterpret_cast<const float4*>(&h[(size_t)s * C + q * 4]);
        acc.x += v.x; acc.y += v.y; acc.z += v.z; acc.w += v.w;
    }
    const float d = dis[node];
    float4 r;
    r.x = fmaf(acc.x, d, b[q * 4 + 0]);
    r.y = fmaf(acc.y, d, b[q * 4 + 1]);
    r.z = fmaf(acc.z, d, b[q * 4 + 2]);
    r.w = fmaf(acc.w, d, b[q * 4 + 3]);
    r.x = r.x > 0.0f ? r.x : 0.0f;
    r.y = r.y > 0.0f ? r.y : 0.0f;
    r.z = r.z > 0.0f ? r.z : 0.0f;
    r.w = r.w > 0.0f ? r.w : 0.0f;
    *reinterpret_cast<float4*>(&out[(size_t)node * C + q * 4]) = r;
}

// ---- pooling (run-length, batch sorted) + head -----------------------------
__global__ void pool_kernel(const float* __restrict__ x3, const int* __restrict__ batch,
                            float* __restrict__ pooled, float* __restrict__ counts, int N) {
    const long long tid = (long long)blockIdx.x * blockDim.x + threadIdx.x;
    const int ch = (int)(tid % 32);
    int n = (int)(tid / 32) * 8;
    if (n >= N) return;
    const int nEnd = (n + 8 < N) ? n + 8 : N;
    int g = batch[n];
    float acc = 0.0f, cnt = 0.0f;
    for (; n < nEnd; ++n) {
        const int gn = batch[n];
        if (gn != g) {
            atomicAdd(&pooled[g * 32 + ch], acc);
            if (ch == 0) atomicAdd(&counts[g], cnt);
            acc = 0.0f; cnt = 0.0f; g = gn;
        }
        acc += x3[(size_t)n * 32 + ch];
        cnt += 1.0f;
    }
    atomicAdd(&pooled[g * 32 + ch], acc);
    if (ch == 0) atomicAdd(&counts[g], cnt);
}

__global__ void head_kernel(const float* __restrict__ pooled, const float* __restrict__ counts,
                            const float* __restrict__ Wl, const float* __restrict__ bl,
                            float* __restrict__ out) {
    __shared__ float p[32];
    const int g = blockIdx.x;
    if (threadIdx.x < 32) {
        float cnt = counts[g];
        cnt = cnt < 1.0f ? 1.0f : cnt;
        p[threadIdx.x] = pooled[g * 32 + threadIdx.x] / cnt;
    }
    __syncthreads();
    const int j = threadIdx.x;  // blockDim.x == 768
    float acc = bl[j];
#pragma unroll
    for (int k = 0; k < 32; ++k) acc = fmaf(p[k], Wl[k * 768 + j], acc);
    out[g * 768 + j] = acc;
}

// ---------------------------------------------------------------------------

extern "C" void kernel_launch(void* const* d_in, const int* in_sizes, int n_in,
                              void* d_out, int out_size, void* d_ws, size_t ws_size,
                              hipStream_t stream) {
    const float* x   = (const float*)d_in[0];
    const float* W1  = (const float*)d_in[1];
    const float* b1  = (const float*)d_in[2];
    const float* W2  = (const float*)d_in[3];
    const float* b2  = (const float*)d_in[4];
    const float* W3  = (const float*)d_in[5];
    const float* b3  = (const float*)d_in[6];
    const float* Wl  = (const float*)d_in[7];
    const float* bl  = (const float*)d_in[8];
    const int* ei    = (const int*)d_in[9];
    const int* batch = (const int*)d_in[10];

    const int N = in_sizes[0] / 128;    // 40000
    const int E = in_sizes[9] / 2;      // 640000
    const int G = out_size / 768;       // 256
    const int NB = (N + 255) / 256;     // scan blocks (<= 256 required)

    const int* src = ei;
    const int* dst = ei + E;
    float* out = (float*)d_out;

    // Workspace:
    //  floats: H[N*128] | A[N*128] | B[N*64] | dis[N] | pooled[G*32] | counts[G]
    //  ints:   deg[N] | off[N+1] | cursor[N] | bsums[256] | csr_src[E]
    float* H      = (float*)d_ws;
    float* A      = H + (size_t)N * 128;
    float* Bb     = A + (size_t)N * 128;
    float* dis    = Bb + (size_t)N * 64;
    float* pooled = dis + N;
    float* counts = pooled + (size_t)G * 32;
    int* deg      = (int*)(counts + G);
    int* off      = deg + N;
    int* cursor   = off + (N + 1);
    int* bsums    = cursor + N;
    int* csr_src  = bsums + 256;

    // ---- CSR build (every launch; ws is re-poisoned) ----
    hipMemsetAsync(deg, 0, (size_t)N * sizeof(int), stream);
    hipMemsetAsync(pooled, 0, ((size_t)G * 32 + G) * sizeof(float), stream);
    deg_count_kernel<<<(E + 255) / 256, 256, 0, stream>>>(dst, deg, E);
    scan1_kernel<<<NB, 256, 0, stream>>>(deg, off, bsums, N);
    scan2_kernel<<<1, 256, 0, stream>>>(bsums, NB);
    scan3_kernel<<<NB, 256, 0, stream>>>(off, bsums, cursor, deg, dis, N, E);
    fill_csr_kernel<<<(E + 255) / 256, 256, 0, stream>>>(src, dst, cursor, csr_src, E);

    // ---- Layer 1: 128 -> 128 : x -> A   (NPB = 64)
    gemm_scale_kernel<128, 128, 4><<<(N + 63) / 64, 256, 0, stream>>>(x, W1, dis, H, N);
    gather_kernel<128><<<(int)(((long long)N * 32 + 255) / 256), 256, 0, stream>>>(
        H, off, csr_src, dis, b1, A, N);

    // ---- Layer 2: 128 -> 64 : A -> B    (NPB = 64)
    gemm_scale_kernel<128, 64, 2><<<(N + 63) / 64, 256, 0, stream>>>(A, W2, dis, H, N);
    gather_kernel<64><<<(int)(((long long)N * 16 + 255) / 256), 256, 0, stream>>>(
        H, off, csr_src, dis, b2, Bb, N);

    // ---- Layer 3: 64 -> 32 : B -> A     (NPB = 128)
    gemm_scale_kernel<64, 32, 2><<<(N + 127) / 128, 256, 0, stream>>>(Bb, W3, dis, H, N);
    gather_kernel<32><<<(int)(((long long)N * 8 + 255) / 256), 256, 0, stream>>>(
        H, off, csr_src, dis, b3, A, N);

    // ---- Global mean pool + head
    pool_kernel<<<(int)(((long long)((N + 7) / 8) * 32 + 255) / 256), 256, 0, stream>>>(
        A, batch, pooled, counts, N);
    head_kernel<<<G, 768, 0, stream>>>(pooled, counts, Wl, bl, out);
}

// Round 6
// 270.239 us; speedup vs baseline: 1.4391x; 1.1084x over previous
//
#include <hip/hip_runtime.h>
#include <hip/hip_fp16.h>

// ---------------------------------------------------------------------------
// TorsoGCNv1: 3x GCNConv(+ReLU) -> global mean pool -> Linear head
// Round 6: h (GEMM output / gather input) stored as fp16 -> halves gather
// traffic. Gather: 8 channels per lane (one 16B load/edge/lane), f32 accum.
// ---------------------------------------------------------------------------

struct H8 { __half2 a, b, c, d; };   // 8 fp16 channels = 16 B

// ---- CSR build -------------------------------------------------------------

__global__ void deg_count_kernel(const int* __restrict__ dst, int* __restrict__ deg, int E) {
    int e = blockIdx.x * blockDim.x + threadIdx.x;
    if (e < E) atomicAdd(&deg[dst[e]], 1);
}

__global__ void scan1_kernel(const int* __restrict__ deg, int* __restrict__ off,
                             int* __restrict__ bsums, int N) {
    __shared__ int s[256];
    const int tid = threadIdx.x;
    const int i = blockIdx.x * 256 + tid;
    const int v = (i < N) ? deg[i] : 0;
    s[tid] = v;
    __syncthreads();
    for (int o = 1; o < 256; o <<= 1) {
        int t = (tid >= o) ? s[tid - o] : 0;
        __syncthreads();
        s[tid] += t;
        __syncthreads();
    }
    if (i < N) off[i] = s[tid] - v;            // exclusive within block
    if (tid == 255) bsums[blockIdx.x] = s[255];
}

__global__ void scan2_kernel(int* __restrict__ bsums, int NB) {
    __shared__ int s[256];
    const int tid = threadIdx.x;
    const int v = (tid < NB) ? bsums[tid] : 0;
    s[tid] = v;
    __syncthreads();
    for (int o = 1; o < 256; o <<= 1) {
        int t = (tid >= o) ? s[tid - o] : 0;
        __syncthreads();
        s[tid] += t;
        __syncthreads();
    }
    if (tid < NB) bsums[tid] = s[tid] - v;
}

__global__ void scan3_kernel(int* __restrict__ off, const int* __restrict__ bsums,
                             int* __restrict__ cursor, const int* __restrict__ deg,
                             float* __restrict__ dis, int N, int E) {
    const int i = blockIdx.x * 256 + threadIdx.x;
    if (i < N) {
        const int o = off[i] + bsums[blockIdx.x];
        off[i] = o;
        cursor[i] = o;
        dis[i] = rsqrtf((float)deg[i] + 1.0f);
    }
    if (i == 0) off[N] = E;
}

__global__ void fill_csr_kernel(const int* __restrict__ src, const int* __restrict__ dst,
                                int* __restrict__ cursor, int* __restrict__ csr_src, int E) {
    int e = blockIdx.x * blockDim.x + threadIdx.x;
    if (e < E) {
        const int pos = atomicAdd(&cursor[dst[e]], 1);
        csr_src[pos] = src[e];
    }
}

// ---- dense: h[n][c] = fp16( dis[n] * sum_k x[n][k] * W[k][c] ) -------------
// x (f32) and W staged in LDS per K-stage of 32; conflict-free layouts.
// Output converted to fp16 (one 16B store of 8 channels per node-chunk).
template <int K, int C, int NR>
__global__ __launch_bounds__(256, 4) void gemm_scale_kernel(
        const float* __restrict__ x, const float* __restrict__ W,
        const float* __restrict__ dis, __half* __restrict__ h, int N) {
    constexpr int TC     = C / 8;         // c-chunks
    constexpr int TN     = 256 / TC;      // threads along n
    constexpr int NPB    = NR * TN;       // nodes per block
    constexpr int KSTAGE = 32;
    constexpr int XROW   = KSTAGE + 4;    // 36 floats
    constexpr int WROW   = TC * 12;
    __shared__ float Xs[NPB * XROW];
    __shared__ float Ws[KSTAGE * WROW];

    const int tc = threadIdx.x % TC;
    const int tn = threadIdx.x / TC;
    const int c0 = tc * 8;
    const int nBase = blockIdx.x * NPB;
    const int n0 = nBase + tn * NR;

    float acc[NR][8] = {};

#pragma unroll 1
    for (int ks = 0; ks < K; ks += KSTAGE) {
        for (int idx = threadIdx.x; idx < KSTAGE * (C / 4); idx += 256) {
            const int k  = idx / (C / 4);
            const int f4 = idx % (C / 4);
            const int t  = f4 >> 1;
            const int hh = f4 & 1;
            *reinterpret_cast<float4*>(&Ws[k * WROW + t * 12 + hh * 4]) =
                *reinterpret_cast<const float4*>(&W[(size_t)(ks + k) * C + t * 8 + hh * 4]);
        }
        for (int idx = threadIdx.x; idx < NPB * (KSTAGE / 4); idx += 256) {
            const int row = idx / (KSTAGE / 4);
            const int c4  = (idx % (KSTAGE / 4)) * 4;
            const int nn  = nBase + row;
            const float4 v = (nn < N)
                ? *reinterpret_cast<const float4*>(&x[(size_t)nn * K + ks + c4])
                : float4{0.f, 0.f, 0.f, 0.f};
            *reinterpret_cast<float4*>(&Xs[row * XROW + c4]) = v;
        }
        __syncthreads();

#pragma unroll 2
        for (int k = 0; k < KSTAGE; k += 4) {
            float4 xv[NR];
#pragma unroll
            for (int i = 0; i < NR; ++i)
                xv[i] = *reinterpret_cast<const float4*>(&Xs[(tn * NR + i) * XROW + k]);
#pragma unroll
            for (int kk = 0; kk < 4; ++kk) {
                float wv[8];
                *reinterpret_cast<float4*>(&wv[0]) =
                    *reinterpret_cast<const float4*>(&Ws[(k + kk) * WROW + tc * 12]);
                *reinterpret_cast<float4*>(&wv[4]) =
                    *reinterpret_cast<const float4*>(&Ws[(k + kk) * WROW + tc * 12 + 4]);
#pragma unroll
                for (int i = 0; i < NR; ++i) {
                    const float xs = (&xv[i].x)[kk];
#pragma unroll
                    for (int j = 0; j < 8; ++j) acc[i][j] = fmaf(xs, wv[j], acc[i][j]);
                }
            }
        }
        __syncthreads();
    }

#pragma unroll
    for (int i = 0; i < NR; ++i) {
        const int nn = n0 + i;
        if (nn < N) {
            const float d = dis[nn];
            H8 o;
            o.a = __floats2half2_rn(acc[i][0] * d, acc[i][1] * d);
            o.b = __floats2half2_rn(acc[i][2] * d, acc[i][3] * d);
            o.c = __floats2half2_rn(acc[i][4] * d, acc[i][5] * d);
            o.d = __floats2half2_rn(acc[i][6] * d, acc[i][7] * d);
            *reinterpret_cast<H8*>(&h[(size_t)nn * C + c0]) = o;
        }
    }
}

// ---- aggregate (gather, fp16 in / f32 out) + self-loop + bias + ReLU ------
__device__ inline void acc_h8(float* acc, const H8& v) {
    float2 f;
    f = __half22float2(v.a); acc[0] += f.x; acc[1] += f.y;
    f = __half22float2(v.b); acc[2] += f.x; acc[3] += f.y;
    f = __half22float2(v.c); acc[4] += f.x; acc[5] += f.y;
    f = __half22float2(v.d); acc[6] += f.x; acc[7] += f.y;
}

template <int C>
__global__ void gather_kernel(const __half* __restrict__ h, const int* __restrict__ off,
                              const int* __restrict__ csr_src, const float* __restrict__ dis,
                              const float* __restrict__ b, float* __restrict__ out, int N) {
    constexpr int CQ = C / 8;            // lanes per node, 8 channels (16B) each
    const long long tid = (long long)blockIdx.x * blockDim.x + threadIdx.x;
    const int node = (int)(tid / CQ);
    const int q    = (int)(tid % CQ);
    if (node >= N) return;

    const int beg = off[node];
    const int end = off[node + 1];

    float acc[8] = {};
    acc_h8(acc, *reinterpret_cast<const H8*>(&h[(size_t)node * C + q * 8]));  // self loop

    int i = beg;
    for (; i + 4 <= end; i += 4) {
        const int s0 = csr_src[i];
        const int s1 = csr_src[i + 1];
        const int s2 = csr_src[i + 2];
        const int s3 = csr_src[i + 3];
        const H8 v0 = *reinterpret_cast<const H8*>(&h[(size_t)s0 * C + q * 8]);
        const H8 v1 = *reinterpret_cast<const H8*>(&h[(size_t)s1 * C + q * 8]);
        const H8 v2 = *reinterpret_cast<const H8*>(&h[(size_t)s2 * C + q * 8]);
        const H8 v3 = *reinterpret_cast<const H8*>(&h[(size_t)s3 * C + q * 8]);
        acc_h8(acc, v0); acc_h8(acc, v1); acc_h8(acc, v2); acc_h8(acc, v3);
    }
    for (; i < end; ++i) {
        const int s = csr_src[i];
        acc_h8(acc, *reinterpret_cast<const H8*>(&h[(size_t)s * C + q * 8]));
    }

    const float d = dis[node];
    float r[8];
#pragma unroll
    for (int j = 0; j < 8; ++j) {
        float v = fmaf(acc[j], d, b[q * 8 + j]);
        r[j] = v > 0.0f ? v : 0.0f;
    }
    *reinterpret_cast<float4*>(&out[(size_t)node * C + q * 8])     = *reinterpret_cast<float4*>(&r[0]);
    *reinterpret_cast<float4*>(&out[(size_t)node * C + q * 8 + 4]) = *reinterpret_cast<float4*>(&r[4]);
}

// ---- pooling (run-length, batch sorted) + head -----------------------------
__global__ void pool_kernel(const float* __restrict__ x3, const int* __restrict__ batch,
                            float* __restrict__ pooled, float* __restrict__ counts, int N) {
    const long long tid = (long long)blockIdx.x * blockDim.x + threadIdx.x;
    const int ch = (int)(tid % 32);
    int n = (int)(tid / 32) * 8;
    if (n >= N) return;
    const int nEnd = (n + 8 < N) ? n + 8 : N;
    int g = batch[n];
    float acc = 0.0f, cnt = 0.0f;
    for (; n < nEnd; ++n) {
        const int gn = batch[n];
        if (gn != g) {
            atomicAdd(&pooled[g * 32 + ch], acc);
            if (ch == 0) atomicAdd(&counts[g], cnt);
            acc = 0.0f; cnt = 0.0f; g = gn;
        }
        acc += x3[(size_t)n * 32 + ch];
        cnt += 1.0f;
    }
    atomicAdd(&pooled[g * 32 + ch], acc);
    if (ch == 0) atomicAdd(&counts[g], cnt);
}

__global__ void head_kernel(const float* __restrict__ pooled, const float* __restrict__ counts,
                            const float* __restrict__ Wl, const float* __restrict__ bl,
                            float* __restrict__ out) {
    __shared__ float p[32];
    const int g = blockIdx.x;
    if (threadIdx.x < 32) {
        float cnt = counts[g];
        cnt = cnt < 1.0f ? 1.0f : cnt;
        p[threadIdx.x] = pooled[g * 32 + threadIdx.x] / cnt;
    }
    __syncthreads();
    const int j = threadIdx.x;  // blockDim.x == 768
    float acc = bl[j];
#pragma unroll
    for (int k = 0; k < 32; ++k) acc = fmaf(p[k], Wl[k * 768 + j], acc);
    out[g * 768 + j] = acc;
}

// ---------------------------------------------------------------------------

extern "C" void kernel_launch(void* const* d_in, const int* in_sizes, int n_in,
                              void* d_out, int out_size, void* d_ws, size_t ws_size,
                              hipStream_t stream) {
    const float* x   = (const float*)d_in[0];
    const float* W1  = (const float*)d_in[1];
    const float* b1  = (const float*)d_in[2];
    const float* W2  = (const float*)d_in[3];
    const float* b2  = (const float*)d_in[4];
    const float* W3  = (const float*)d_in[5];
    const float* b3  = (const float*)d_in[6];
    const float* Wl  = (const float*)d_in[7];
    const float* bl  = (const float*)d_in[8];
    const int* ei    = (const int*)d_in[9];
    const int* batch = (const int*)d_in[10];

    const int N = in_sizes[0] / 128;    // 40000
    const int E = in_sizes[9] / 2;      // 640000
    const int G = out_size / 768;       // 256
    const int NB = (N + 255) / 256;     // scan blocks (<= 256 required)

    const int* src = ei;
    const int* dst = ei + E;
    float* out = (float*)d_out;

    // Workspace (float-slot layout kept from round 5; H slot reused as fp16):
    //  floats: Hslot[N*128] | A[N*128] | B[N*64] | dis[N] | pooled[G*32] | counts[G]
    //  ints:   deg[N] | off[N+1] | cursor[N] | bsums[256] | csr_src[E]
    float* fws    = (float*)d_ws;
    __half* H     = (__half*)fws;                 // N*128 halves (uses half the slot)
    float* A      = fws + (size_t)N * 128;
    float* Bb     = A + (size_t)N * 128;
    float* dis    = Bb + (size_t)N * 64;
    float* pooled = dis + N;
    float* counts = pooled + (size_t)G * 32;
    int* deg      = (int*)(counts + G);
    int* off      = deg + N;
    int* cursor   = off + (N + 1);
    int* bsums    = cursor + N;
    int* csr_src  = bsums + 256;

    // ---- CSR build (every launch; ws is re-poisoned) ----
    hipMemsetAsync(deg, 0, (size_t)N * sizeof(int), stream);
    hipMemsetAsync(pooled, 0, ((size_t)G * 32 + G) * sizeof(float), stream);
    deg_count_kernel<<<(E + 255) / 256, 256, 0, stream>>>(dst, deg, E);
    scan1_kernel<<<NB, 256, 0, stream>>>(deg, off, bsums, N);
    scan2_kernel<<<1, 256, 0, stream>>>(bsums, NB);
    scan3_kernel<<<NB, 256, 0, stream>>>(off, bsums, cursor, deg, dis, N, E);
    fill_csr_kernel<<<(E + 255) / 256, 256, 0, stream>>>(src, dst, cursor, csr_src, E);

    // ---- Layer 1: 128 -> 128 : x -> A
    gemm_scale_kernel<128, 128, 4><<<(N + 63) / 64, 256, 0, stream>>>(x, W1, dis, H, N);
    gather_kernel<128><<<(int)(((long long)N * 16 + 255) / 256), 256, 0, stream>>>(
        H, off, csr_src, dis, b1, A, N);

    // ---- Layer 2: 128 -> 64 : A -> B
    gemm_scale_kernel<128, 64, 2><<<(N + 63) / 64, 256, 0, stream>>>(A, W2, dis, H, N);
    gather_kernel<64><<<(int)(((long long)N * 8 + 255) / 256), 256, 0, stream>>>(
        H, off, csr_src, dis, b2, Bb, N);

    // ---- Layer 3: 64 -> 32 : B -> A
    gemm_scale_kernel<64, 32, 2><<<(N + 127) / 128, 256, 0, stream>>>(Bb, W3, dis, H, N);
    gather_kernel<32><<<(int)(((long long)N * 4 + 255) / 256), 256, 0, stream>>>(
        H, off, csr_src, dis, b3, A, N);

    // ---- Global mean pool + head
    pool_kernel<<<(int)(((long long)((N + 7) / 8) * 32 + 255) / 256), 256, 0, stream>>>(
        A, batch, pooled, counts, N);
    head_kernel<<<G, 768, 0, stream>>>(pooled, counts, Wl, bl, out);
}

// Round 7
// 269.048 us; speedup vs baseline: 1.4455x; 1.0044x over previous
//
#include <hip/hip_runtime.h>
#include <hip/hip_fp16.h>

// ---------------------------------------------------------------------------
// TorsoGCNv1: 3x GCNConv(+ReLU) -> global mean pool -> Linear head
// Round 7: fp16 activations end-to-end (h AND inter-layer A/B), gather with
// 8-deep unroll, fused pool+head (binary search on sorted batch, no atomics).
// ---------------------------------------------------------------------------

struct H8 { __half2 a, b, c, d; };   // 8 fp16 channels = 16 B

// ---- CSR build -------------------------------------------------------------

__global__ void deg_count_kernel(const int* __restrict__ dst, int* __restrict__ deg, int E) {
    int e = blockIdx.x * blockDim.x + threadIdx.x;
    if (e < E) atomicAdd(&deg[dst[e]], 1);
}

__global__ void scan1_kernel(const int* __restrict__ deg, int* __restrict__ off,
                             int* __restrict__ bsums, int N) {
    __shared__ int s[256];
    const int tid = threadIdx.x;
    const int i = blockIdx.x * 256 + tid;
    const int v = (i < N) ? deg[i] : 0;
    s[tid] = v;
    __syncthreads();
    for (int o = 1; o < 256; o <<= 1) {
        int t = (tid >= o) ? s[tid - o] : 0;
        __syncthreads();
        s[tid] += t;
        __syncthreads();
    }
    if (i < N) off[i] = s[tid] - v;            // exclusive within block
    if (tid == 255) bsums[blockIdx.x] = s[255];
}

__global__ void scan2_kernel(int* __restrict__ bsums, int NB) {
    __shared__ int s[256];
    const int tid = threadIdx.x;
    const int v = (tid < NB) ? bsums[tid] : 0;
    s[tid] = v;
    __syncthreads();
    for (int o = 1; o < 256; o <<= 1) {
        int t = (tid >= o) ? s[tid - o] : 0;
        __syncthreads();
        s[tid] += t;
        __syncthreads();
    }
    if (tid < NB) bsums[tid] = s[tid] - v;
}

__global__ void scan3_kernel(int* __restrict__ off, const int* __restrict__ bsums,
                             int* __restrict__ cursor, const int* __restrict__ deg,
                             float* __restrict__ dis, int N, int E) {
    const int i = blockIdx.x * 256 + threadIdx.x;
    if (i < N) {
        const int o = off[i] + bsums[blockIdx.x];
        off[i] = o;
        cursor[i] = o;
        dis[i] = rsqrtf((float)deg[i] + 1.0f);
    }
    if (i == 0) off[N] = E;
}

__global__ void fill_csr_kernel(const int* __restrict__ src, const int* __restrict__ dst,
                                int* __restrict__ cursor, int* __restrict__ csr_src, int E) {
    int e = blockIdx.x * blockDim.x + threadIdx.x;
    if (e < E) {
        const int pos = atomicAdd(&cursor[dst[e]], 1);
        csr_src[pos] = src[e];
    }
}

// ---- dense: h[n][c] = fp16( dis[n] * sum_k x[n][k] * W[k][c] ) -------------
// Input x is f32 (layer 1) or fp16 (layers 2,3) -> converted to f32 in LDS.
// W staged swizzled (chunk stride 12 floats); Xs row stride 36 floats.
template <int K, int C, int NR, bool HALF_IN>
__global__ __launch_bounds__(256, 4) void gemm_scale_kernel(
        const void* __restrict__ x_, const float* __restrict__ W,
        const float* __restrict__ dis, __half* __restrict__ h, int N) {
    constexpr int TC     = C / 8;         // c-chunks
    constexpr int TN     = 256 / TC;      // threads along n
    constexpr int NPB    = NR * TN;       // nodes per block
    constexpr int KSTAGE = 32;
    constexpr int XROW   = KSTAGE + 4;    // 36 floats
    constexpr int WROW   = TC * 12;
    __shared__ float Xs[NPB * XROW];
    __shared__ float Ws[KSTAGE * WROW];

    const int tc = threadIdx.x % TC;
    const int tn = threadIdx.x / TC;
    const int c0 = tc * 8;
    const int nBase = blockIdx.x * NPB;
    const int n0 = nBase + tn * NR;

    float acc[NR][8] = {};

#pragma unroll 1
    for (int ks = 0; ks < K; ks += KSTAGE) {
        // stage W (swizzled chunks)
        for (int idx = threadIdx.x; idx < KSTAGE * (C / 4); idx += 256) {
            const int k  = idx / (C / 4);
            const int f4 = idx % (C / 4);
            const int t  = f4 >> 1;
            const int hh = f4 & 1;
            *reinterpret_cast<float4*>(&Ws[k * WROW + t * 12 + hh * 4]) =
                *reinterpret_cast<const float4*>(&W[(size_t)(ks + k) * C + t * 8 + hh * 4]);
        }
        // stage x tile (coalesced 16B chunks)
        if (HALF_IN) {
            const __half* xh = (const __half*)x_;
            for (int idx = threadIdx.x; idx < NPB * (KSTAGE / 8); idx += 256) {
                const int row = idx / (KSTAGE / 8);
                const int c8  = (idx % (KSTAGE / 8)) * 8;
                const int nn  = nBase + row;
                float f[8];
                if (nn < N) {
                    const H8 v = *reinterpret_cast<const H8*>(&xh[(size_t)nn * K + ks + c8]);
                    float2 t2;
                    t2 = __half22float2(v.a); f[0] = t2.x; f[1] = t2.y;
                    t2 = __half22float2(v.b); f[2] = t2.x; f[3] = t2.y;
                    t2 = __half22float2(v.c); f[4] = t2.x; f[5] = t2.y;
                    t2 = __half22float2(v.d); f[6] = t2.x; f[7] = t2.y;
                } else {
#pragma unroll
                    for (int j = 0; j < 8; ++j) f[j] = 0.0f;
                }
                *reinterpret_cast<float4*>(&Xs[row * XROW + c8])     = *reinterpret_cast<float4*>(&f[0]);
                *reinterpret_cast<float4*>(&Xs[row * XROW + c8 + 4]) = *reinterpret_cast<float4*>(&f[4]);
            }
        } else {
            const float* xf = (const float*)x_;
            for (int idx = threadIdx.x; idx < NPB * (KSTAGE / 4); idx += 256) {
                const int row = idx / (KSTAGE / 4);
                const int c4  = (idx % (KSTAGE / 4)) * 4;
                const int nn  = nBase + row;
                const float4 v = (nn < N)
                    ? *reinterpret_cast<const float4*>(&xf[(size_t)nn * K + ks + c4])
                    : float4{0.f, 0.f, 0.f, 0.f};
                *reinterpret_cast<float4*>(&Xs[row * XROW + c4]) = v;
            }
        }
        __syncthreads();

#pragma unroll 2
        for (int k = 0; k < KSTAGE; k += 4) {
            float4 xv[NR];
#pragma unroll
            for (int i = 0; i < NR; ++i)
                xv[i] = *reinterpret_cast<const float4*>(&Xs[(tn * NR + i) * XROW + k]);
#pragma unroll
            for (int kk = 0; kk < 4; ++kk) {
                float wv[8];
                *reinterpret_cast<float4*>(&wv[0]) =
                    *reinterpret_cast<const float4*>(&Ws[(k + kk) * WROW + tc * 12]);
                *reinterpret_cast<float4*>(&wv[4]) =
                    *reinterpret_cast<const float4*>(&Ws[(k + kk) * WROW + tc * 12 + 4]);
#pragma unroll
                for (int i = 0; i < NR; ++i) {
                    const float xs = (&xv[i].x)[kk];
#pragma unroll
                    for (int j = 0; j < 8; ++j) acc[i][j] = fmaf(xs, wv[j], acc[i][j]);
                }
            }
        }
        __syncthreads();
    }

#pragma unroll
    for (int i = 0; i < NR; ++i) {
        const int nn = n0 + i;
        if (nn < N) {
            const float d = dis[nn];
            H8 o;
            o.a = __floats2half2_rn(acc[i][0] * d, acc[i][1] * d);
            o.b = __floats2half2_rn(acc[i][2] * d, acc[i][3] * d);
            o.c = __floats2half2_rn(acc[i][4] * d, acc[i][5] * d);
            o.d = __floats2half2_rn(acc[i][6] * d, acc[i][7] * d);
            *reinterpret_cast<H8*>(&h[(size_t)nn * C + c0]) = o;
        }
    }
}

// ---- aggregate (gather, fp16 in / fp16 out) + self-loop + bias + ReLU -----
__device__ inline void acc_h8(float* acc, const H8& v) {
    float2 f;
    f = __half22float2(v.a); acc[0] += f.x; acc[1] += f.y;
    f = __half22float2(v.b); acc[2] += f.x; acc[3] += f.y;
    f = __half22float2(v.c); acc[4] += f.x; acc[5] += f.y;
    f = __half22float2(v.d); acc[6] += f.x; acc[7] += f.y;
}

template <int C>
__global__ void gather_kernel(const __half* __restrict__ h, const int* __restrict__ off,
                              const int* __restrict__ csr_src, const float* __restrict__ dis,
                              const float* __restrict__ b, __half* __restrict__ out, int N) {
    constexpr int CQ = C / 8;            // lanes per node, 8 channels (16B) each
    const long long tid = (long long)blockIdx.x * blockDim.x + threadIdx.x;
    const int node = (int)(tid / CQ);
    const int q    = (int)(tid % CQ);
    if (node >= N) return;

    const int beg = off[node];
    const int end = off[node + 1];

    float acc[8] = {};
    acc_h8(acc, *reinterpret_cast<const H8*>(&h[(size_t)node * C + q * 8]));  // self loop

    int i = beg;
    for (; i + 8 <= end; i += 8) {
        int s[8];
#pragma unroll
        for (int u = 0; u < 8; ++u) s[u] = csr_src[i + u];
        H8 v[8];
#pragma unroll
        for (int u = 0; u < 8; ++u) v[u] = *reinterpret_cast<const H8*>(&h[(size_t)s[u] * C + q * 8]);
#pragma unroll
        for (int u = 0; u < 8; ++u) acc_h8(acc, v[u]);
    }
    for (; i < end; ++i) {
        const int s = csr_src[i];
        acc_h8(acc, *reinterpret_cast<const H8*>(&h[(size_t)s * C + q * 8]));
    }

    const float d = dis[node];
    float r[8];
#pragma unroll
    for (int j = 0; j < 8; ++j) {
        float v = fmaf(acc[j], d, b[q * 8 + j]);
        r[j] = v > 0.0f ? v : 0.0f;
    }
    H8 o;
    o.a = __floats2half2_rn(r[0], r[1]);
    o.b = __floats2half2_rn(r[2], r[3]);
    o.c = __floats2half2_rn(r[4], r[5]);
    o.d = __floats2half2_rn(r[6], r[7]);
    *reinterpret_cast<H8*>(&out[(size_t)node * C + q * 8]) = o;
}

// ---- fused global-mean-pool + head -----------------------------------------
// One block per graph. batch is sorted -> binary search node range [lo, hi).
// x3: [N,32] fp16. out[g][j] = (mean x3 rows) . Wl[:,j] + bl[j], j < 768.
__global__ __launch_bounds__(256) void poolhead_kernel(
        const __half* __restrict__ x3, const int* __restrict__ batch,
        const float* __restrict__ Wl, const float* __restrict__ bl,
        float* __restrict__ out, int N) {
    const int g = blockIdx.x;
    __shared__ int bounds[2];
    if (threadIdx.x == 0) {
        int lo = 0, hi = N;
        while (lo < hi) { int m = (lo + hi) >> 1; if (batch[m] <  g) lo = m + 1; else hi = m; }
        bounds[0] = lo;
        int lo2 = lo, hi2 = N;
        while (lo2 < hi2) { int m = (lo2 + hi2) >> 1; if (batch[m] <= g) lo2 = m + 1; else hi2 = m; }
        bounds[1] = lo2;
    }
    __syncthreads();
    const int lo = bounds[0], hi = bounds[1];

    // 256 threads = 8 row-groups x 32 channels
    const int ch  = threadIdx.x & 31;
    const int grp = threadIdx.x >> 5;
    float acc = 0.0f;
    for (int n = lo + grp; n < hi; n += 8)
        acc += __half2float(x3[(size_t)n * 32 + ch]);

    __shared__ float red[8][33];
    red[grp][ch] = acc;
    __syncthreads();
    __shared__ float p[32];
    if (grp == 0) {
        float s = red[0][ch] + red[1][ch] + red[2][ch] + red[3][ch]
                + red[4][ch] + red[5][ch] + red[6][ch] + red[7][ch];
        float cnt = (float)(hi - lo);
        cnt = cnt < 1.0f ? 1.0f : cnt;
        p[ch] = s / cnt;
    }
    __syncthreads();

    for (int j = threadIdx.x; j < 768; j += 256) {
        float a = bl[j];
#pragma unroll
        for (int k = 0; k < 32; ++k) a = fmaf(p[k], Wl[k * 768 + j], a);
        out[g * 768 + j] = a;
    }
}

// ---------------------------------------------------------------------------

extern "C" void kernel_launch(void* const* d_in, const int* in_sizes, int n_in,
                              void* d_out, int out_size, void* d_ws, size_t ws_size,
                              hipStream_t stream) {
    const float* x   = (const float*)d_in[0];
    const float* W1  = (const float*)d_in[1];
    const float* b1  = (const float*)d_in[2];
    const float* W2  = (const float*)d_in[3];
    const float* b2  = (const float*)d_in[4];
    const float* W3  = (const float*)d_in[5];
    const float* b3  = (const float*)d_in[6];
    const float* Wl  = (const float*)d_in[7];
    const float* bl  = (const float*)d_in[8];
    const int* ei    = (const int*)d_in[9];
    const int* batch = (const int*)d_in[10];

    const int N = in_sizes[0] / 128;    // 40000
    const int E = in_sizes[9] / 2;      // 640000
    const int G = out_size / 768;       // 256
    const int NB = (N + 255) / 256;     // scan blocks (<= 256 required)

    const int* src = ei;
    const int* dst = ei + E;
    float* out = (float*)d_out;

    // Workspace:
    //  halves: H[N*128] | A[N*128] | B[N*64]
    //  floats: dis[N]
    //  ints:   deg[N] | off[N+1] | cursor[N] | bsums[256] | csr_src[E]
    __half* H     = (__half*)d_ws;
    __half* A     = H + (size_t)N * 128;
    __half* Bb    = A + (size_t)N * 128;
    float* dis    = (float*)(Bb + (size_t)N * 64);
    int* deg      = (int*)(dis + N);
    int* off      = deg + N;
    int* cursor   = off + (N + 1);
    int* bsums    = cursor + N;
    int* csr_src  = bsums + 256;

    // ---- CSR build (every launch; ws is re-poisoned) ----
    hipMemsetAsync(deg, 0, (size_t)N * sizeof(int), stream);
    deg_count_kernel<<<(E + 255) / 256, 256, 0, stream>>>(dst, deg, E);
    scan1_kernel<<<NB, 256, 0, stream>>>(deg, off, bsums, N);
    scan2_kernel<<<1, 256, 0, stream>>>(bsums, NB);
    scan3_kernel<<<NB, 256, 0, stream>>>(off, bsums, cursor, deg, dis, N, E);
    fill_csr_kernel<<<(E + 255) / 256, 256, 0, stream>>>(src, dst, cursor, csr_src, E);

    // ---- Layer 1: 128 -> 128 : x(f32) -> H -> A(fp16)
    gemm_scale_kernel<128, 128, 4, false><<<(N + 63) / 64, 256, 0, stream>>>(x, W1, dis, H, N);
    gather_kernel<128><<<(int)(((long long)N * 16 + 255) / 256), 256, 0, stream>>>(
        H, off, csr_src, dis, b1, A, N);

    // ---- Layer 2: 128 -> 64 : A(fp16) -> H -> B(fp16)
    gemm_scale_kernel<128, 64, 2, true><<<(N + 63) / 64, 256, 0, stream>>>(A, W2, dis, H, N);
    gather_kernel<64><<<(int)(((long long)N * 8 + 255) / 256), 256, 0, stream>>>(
        H, off, csr_src, dis, b2, Bb, N);

    // ---- Layer 3: 64 -> 32 : B(fp16) -> H -> A(fp16, reused as x3)
    gemm_scale_kernel<64, 32, 2, true><<<(N + 127) / 128, 256, 0, stream>>>(Bb, W3, dis, H, N);
    gather_kernel<32><<<(int)(((long long)N * 4 + 255) / 256), 256, 0, stream>>>(
        H, off, csr_src, dis, b3, A, N);

    // ---- Fused global mean pool + head
    poolhead_kernel<<<G, 256, 0, stream>>>(A, batch, Wl, bl, out, N);
}